// Round 1
// baseline (778.742 us; speedup 1.0000x reference)
//
#include <hip/hip_runtime.h>

#define NN 50000
#define EE 800000
// IN = HID = 128, BASES*FH = 64, HEADS*BASES = 32

// ---------------- degree / symnorm ----------------
__global__ void k_deg_init(float* deg, int n) {
    int i = blockIdx.x * blockDim.x + threadIdx.x;
    if (i < n) deg[i] = 1.0f;   // self loop
}

__global__ void k_deg_acc(const int* __restrict__ col, float* deg, int e) {
    int i = blockIdx.x * blockDim.x + threadIdx.x;
    if (i < e) atomicAdd(&deg[col[i]], 1.0f);
}

__global__ void k_dis(float* deg, int n) {
    int i = blockIdx.x * blockDim.x + threadIdx.x;
    if (i < n) {
        float d = deg[i];
        deg[i] = 1.0f / sqrtf(d);   // deg >= 1 always (self loop)
    }
}

// ---------------- fused GEMM: bases = x@Wb ; wcomb = x@Wc + bc ----------------
// thread-per-row, 96 f32 accumulators, W loads are wave-uniform (scalarized)
__global__ __launch_bounds__(256) void k_gemm(
    const float* __restrict__ x, const float* __restrict__ Wb,
    const float* __restrict__ Wc, const float* __restrict__ bc,
    float* __restrict__ bases, float* __restrict__ wcomb, int n)
{
    int row = blockIdx.x * 256 + threadIdx.x;
    if (row >= n) return;
    float accB[64];
    float accC[32];
#pragma unroll
    for (int c = 0; c < 64; c++) accB[c] = 0.f;
#pragma unroll
    for (int c = 0; c < 32; c++) accC[c] = 0.f;

    const float4* xr = (const float4*)(x + (size_t)row * 128);
    for (int k4 = 0; k4 < 32; k4++) {
        float4 xv = xr[k4];
#pragma unroll
        for (int j = 0; j < 4; j++) {
            float xs = (j == 0) ? xv.x : (j == 1) ? xv.y : (j == 2) ? xv.z : xv.w;
            int k = k4 * 4 + j;
            const float* wbk = Wb + k * 64;
            const float* wck = Wc + k * 32;
#pragma unroll
            for (int c = 0; c < 64; c++) accB[c] = fmaf(xs, wbk[c], accB[c]);
#pragma unroll
            for (int c = 0; c < 32; c++) accC[c] = fmaf(xs, wck[c], accC[c]);
        }
    }
    float4* bo = (float4*)(bases + (size_t)row * 64);
#pragma unroll
    for (int c = 0; c < 16; c++)
        bo[c] = make_float4(accB[4*c], accB[4*c+1], accB[4*c+2], accB[4*c+3]);
    float4* wo = (float4*)(wcomb + (size_t)row * 32);
#pragma unroll
    for (int c = 0; c < 8; c++)
        wo[c] = make_float4(accC[4*c] + bc[4*c], accC[4*c+1] + bc[4*c+1],
                            accC[4*c+2] + bc[4*c+2], accC[4*c+3] + bc[4*c+3]);
}

// ---------------- aggregate: init with self-loop term ----------------
__global__ void k_agg_init(const float* __restrict__ bases,
                           const float* __restrict__ dis,
                           float* __restrict__ agg, int n64)
{
    int i = blockIdx.x * blockDim.x + threadIdx.x;
    if (i < n64) {
        float d = dis[i >> 6];
        agg[i] = bases[i] * d * d;
    }
}

// ---------------- scatter-add over edges ----------------
__global__ __launch_bounds__(256) void k_scatter(
    const int* __restrict__ ei, const float* __restrict__ dis,
    const float* __restrict__ bases, float* __restrict__ agg, int e)
{
    int t = blockIdx.x * 256 + threadIdx.x;
    int ed = t >> 6, f = t & 63;
    if (ed >= e) return;
    int r = ei[ed];
    int c = ei[e + ed];
    float nrm = dis[r] * dis[c];
    atomicAdd(&agg[c * 64 + f], bases[r * 64 + f] * nrm);
}

// ---------------- per-node combine: h[n,h*16+f] = sum_b w[n,h*4+b]*agg[n,b*16+f] + bias ----------------
__global__ void k_combine(const float* __restrict__ wcomb,
                          const float* __restrict__ agg,
                          const float* __restrict__ bias,
                          float* __restrict__ out, int n128, int do_relu)
{
    int t = blockIdx.x * blockDim.x + threadIdx.x;
    if (t >= n128) return;
    int node = t >> 7, ch = t & 127;
    int hd = ch >> 4, f = ch & 15;
    const float* wn = wcomb + node * 32 + hd * 4;
    const float* an = agg + node * 64 + f;
    float s = bias[ch];
#pragma unroll
    for (int b = 0; b < 4; b++) s = fmaf(wn[b], an[b * 16], s);
    if (do_relu) s = fmaxf(s, 0.f);
    out[t] = s;
}

// ---------------- per-node classifier projections: p[n,4] = [h.Wtop_0, h.Wtop_1, h.Wbot_0, h.Wbot_1] ----------------
__global__ __launch_bounds__(256) void k_cls(
    const float* __restrict__ h, const float* __restrict__ Wcls,
    const float* __restrict__ bcls, float* __restrict__ p, int n)
{
    int t = blockIdx.x * 256 + threadIdx.x;
    int node = t >> 6, l = t & 63;
    if (node >= n) return;
    float a = h[node * 128 + l];
    float b = h[node * 128 + 64 + l];
    float r0 = a * Wcls[l * 2 + 0] + b * Wcls[(64 + l) * 2 + 0];
    float r1 = a * Wcls[l * 2 + 1] + b * Wcls[(64 + l) * 2 + 1];
    float r2 = a * Wcls[(128 + l) * 2 + 0] + b * Wcls[(192 + l) * 2 + 0];
    float r3 = a * Wcls[(128 + l) * 2 + 1] + b * Wcls[(192 + l) * 2 + 1];
#pragma unroll
    for (int off = 32; off; off >>= 1) {
        r0 += __shfl_xor(r0, off, 64);
        r1 += __shfl_xor(r1, off, 64);
        r2 += __shfl_xor(r2, off, 64);
        r3 += __shfl_xor(r3, off, 64);
    }
    if (l == 0) {
        p[node * 4 + 0] = r0 + bcls[0];   // fold bcls into "top" part
        p[node * 4 + 1] = r1 + bcls[1];
        p[node * 4 + 2] = r2;
        p[node * 4 + 3] = r3;
    }
}

// ---------------- edge output: out[e] = p_top[row] + p_bot[col] ----------------
__global__ void k_edge(const int* __restrict__ ei, const float* __restrict__ p,
                       float* __restrict__ out, int e)
{
    int t = blockIdx.x * blockDim.x + threadIdx.x;
    if (t >= e) return;
    int r = ei[t];
    int c = ei[e + t];
    float2 pt = *(const float2*)(p + r * 4);
    float2 pb = *(const float2*)(p + c * 4 + 2);
    float2 o;
    o.x = pt.x + pb.x;
    o.y = pt.y + pb.y;
    *(float2*)(out + t * 2) = o;
}

extern "C" void kernel_launch(void* const* d_in, const int* in_sizes, int n_in,
                              void* d_out, int out_size, void* d_ws, size_t ws_size,
                              hipStream_t stream) {
    const float* x    = (const float*)d_in[0];
    const int*   ei   = (const int*)d_in[1];
    const float* Wb1  = (const float*)d_in[2];
    const float* Wc1  = (const float*)d_in[3];
    const float* bc1  = (const float*)d_in[4];
    const float* b1   = (const float*)d_in[5];
    const float* Wb2  = (const float*)d_in[6];
    const float* Wc2  = (const float*)d_in[7];
    const float* bc2  = (const float*)d_in[8];
    const float* b2   = (const float*)d_in[9];
    const float* Wcls = (const float*)d_in[10];
    const float* bcls = (const float*)d_in[11];
    float* out = (float*)d_out;

    float* ws = (float*)d_ws;
    size_t off = 0;
    float* dis   = ws + off; off += 50048;            // deg -> dis, padded
    float* bases = ws + off; off += (size_t)NN * 64;  // also reused as p[N,4] later
    float* wcomb = ws + off; off += (size_t)NN * 32;
    float* agg   = ws + off; off += (size_t)NN * 64;
    float* h     = ws + off; off += (size_t)NN * 128; // conv1 out, then conv2 out (in place)
    float* p     = bases;                             // overlay: bases dead after conv2 combine

    const int B = 256;
    int gN    = (NN + B - 1) / B;          // 196
    int gE    = (EE + B - 1) / B;          // 3125
    int gN64  = (NN * 64 + B - 1) / B;     // 12500
    int gN128 = (NN * 128 + B - 1) / B;    // 25000
    int gE64  = (int)(((long long)EE * 64 + B - 1) / B); // 200000

    // symnorm weights
    k_deg_init<<<gN, B, 0, stream>>>(dis, NN);
    k_deg_acc<<<gE, B, 0, stream>>>(ei + EE, dis, EE);
    k_dis<<<gN, B, 0, stream>>>(dis, NN);

    // conv1
    k_gemm<<<gN, B, 0, stream>>>(x, Wb1, Wc1, bc1, bases, wcomb, NN);
    k_agg_init<<<gN64, B, 0, stream>>>(bases, dis, agg, NN * 64);
    k_scatter<<<gE64, B, 0, stream>>>(ei, dis, bases, agg, EE);
    k_combine<<<gN128, B, 0, stream>>>(wcomb, agg, b1, h, NN * 128, 1);

    // conv2
    k_gemm<<<gN, B, 0, stream>>>(h, Wb2, Wc2, bc2, bases, wcomb, NN);
    k_agg_init<<<gN64, B, 0, stream>>>(bases, dis, agg, NN * 64);
    k_scatter<<<gE64, B, 0, stream>>>(ei, dis, bases, agg, EE);
    k_combine<<<gN128, B, 0, stream>>>(wcomb, agg, b2, h, NN * 128, 0);

    // edge classifier
    k_cls<<<gN64 /*N*64 threads /256*/, B, 0, stream>>>(h, Wcls, bcls, p, NN);
    k_edge<<<gE, B, 0, stream>>>(ei, p, out, EE);
}

// Round 2
// 388.196 us; speedup vs baseline: 2.0061x; 2.0061x over previous
//
#include <hip/hip_runtime.h>

#define NN 50000
#define EE 800000
// IN = HID = 128, BASES*FH = 64, HEADS*BASES = 32

// ---------------- utility ----------------
__global__ void k_zero_i(int* p, int n) {
    int i = blockIdx.x * blockDim.x + threadIdx.x;
    if (i < n) p[i] = 0;
}

__global__ void k_count(const int* __restrict__ col, int* cnt, int e) {
    int i = blockIdx.x * blockDim.x + threadIdx.x;
    if (i < e) atomicAdd(&cnt[col[i]], 1);
}

__global__ void k_dis(const int* __restrict__ cnt, float* dis, int n) {
    int i = blockIdx.x * blockDim.x + threadIdx.x;
    if (i < n) dis[i] = rsqrtf((float)cnt[i] + 1.0f);  // +1 self loop
}

// ---------------- block scans (exclusive prefix sum over cnt -> starts) ----------------
__global__ void k_scan1(const int* __restrict__ cnt, int* starts, int* bsum, int n) {
    __shared__ int s[256];
    int tid = threadIdx.x;
    int i = blockIdx.x * 256 + tid;
    int v = (i < n) ? cnt[i] : 0;
    s[tid] = v;
    __syncthreads();
    for (int off = 1; off < 256; off <<= 1) {
        int t = 0;
        if (tid >= off) t = s[tid - off];
        __syncthreads();
        if (tid >= off) s[tid] += t;
        __syncthreads();
    }
    if (i < n) starts[i] = s[tid] - v;          // exclusive within block
    if (tid == 255) bsum[blockIdx.x] = s[255];  // block total
}

__global__ void k_scan2(const int* __restrict__ bsum, int* boff, int nb) {
    __shared__ int s[256];
    int tid = threadIdx.x;
    int v = (tid < nb) ? bsum[tid] : 0;
    s[tid] = v;
    __syncthreads();
    for (int off = 1; off < 256; off <<= 1) {
        int t = 0;
        if (tid >= off) t = s[tid - off];
        __syncthreads();
        if (tid >= off) s[tid] += t;
        __syncthreads();
    }
    if (tid < nb) boff[tid] = s[tid] - v;  // exclusive
}

__global__ void k_scan3(int* starts, int* cursor, const int* __restrict__ boff, int n) {
    int i = blockIdx.x * blockDim.x + threadIdx.x;
    if (i < n) {
        int st = starts[i] + boff[i >> 8];
        starts[i] = st;
        cursor[i] = st;
    }
}

__global__ void k_fill(const int* __restrict__ ei, int* cursor, int* csr, int e) {
    int i = blockIdx.x * blockDim.x + threadIdx.x;
    if (i < e) {
        int r = ei[i];
        int c = ei[e + i];
        int pos = atomicAdd(&cursor[c], 1);
        csr[pos] = r;
    }
}

// ---------------- GEMM: column-group split (y=0,1 -> bases*dis ; y=2 -> wcomb) ----------------
__global__ __launch_bounds__(256) void k_gemm(
    const float* __restrict__ x, const float* __restrict__ Wb,
    const float* __restrict__ Wc, const float* __restrict__ bc,
    const float* __restrict__ dis,
    float* __restrict__ bases, float* __restrict__ wcomb, int n)
{
    int row = blockIdx.x * 256 + threadIdx.x;
    int grp = blockIdx.y;  // 0,1: bases cols [grp*32,grp*32+32) ; 2: wcomb
    if (row >= n) return;
    float acc[32];
#pragma unroll
    for (int c = 0; c < 32; c++) acc[c] = 0.f;

    const float* W = (grp < 2) ? (Wb + grp * 32) : Wc;
    int ldw = (grp < 2) ? 64 : 32;

    const float4* xr = (const float4*)(x + (size_t)row * 128);
    for (int k4 = 0; k4 < 32; k4++) {
        float4 xv = xr[k4];
#pragma unroll
        for (int j = 0; j < 4; j++) {
            float xs = (j == 0) ? xv.x : (j == 1) ? xv.y : (j == 2) ? xv.z : xv.w;
            const float* wk = W + (k4 * 4 + j) * ldw;
#pragma unroll
            for (int c = 0; c < 32; c++) acc[c] = fmaf(xs, wk[c], acc[c]);
        }
    }
    if (grp < 2) {
        float d = dis[row];
        float4* bo = (float4*)(bases + (size_t)row * 64 + grp * 32);
#pragma unroll
        for (int c = 0; c < 8; c++)
            bo[c] = make_float4(acc[4*c] * d, acc[4*c+1] * d, acc[4*c+2] * d, acc[4*c+3] * d);
    } else {
        float4* wo = (float4*)(wcomb + (size_t)row * 32);
#pragma unroll
        for (int c = 0; c < 8; c++)
            wo[c] = make_float4(acc[4*c] + bc[4*c], acc[4*c+1] + bc[4*c+1],
                                acc[4*c+2] + bc[4*c+2], acc[4*c+3] + bc[4*c+3]);
    }
}

// ---------------- fused aggregate (CSR gather) + einsum combine + bias (+relu) ----------------
// one wave per node; lane = basis-feature index (b = lane>>4, fh = lane&15)
// bases is pre-scaled by dis[row]; agg = dis[c] * (bases_s[c] + sum_r bases_s[r])
__global__ __launch_bounds__(256) void k_agg(
    const int* __restrict__ csr, const int* __restrict__ starts,
    const int* __restrict__ cnt, const float* __restrict__ bs,
    const float* __restrict__ dis, const float* __restrict__ wcomb,
    const float* __restrict__ bias, float* __restrict__ h, int n, int do_relu)
{
    int wid = (blockIdx.x * 256 + threadIdx.x) >> 6;
    int lane = threadIdx.x & 63;
    if (wid >= n) return;
    int start = starts[wid];
    int deg = cnt[wid];

    float acc = bs[(size_t)wid * 64 + lane];  // self-loop term (pre-scaled)
    int j = 0;
    int r_next = (deg > 0) ? csr[start] : 0;
    for (; j < deg; j++) {
        int r = r_next;
        if (j + 1 < deg) r_next = csr[start + j + 1];
        acc += bs[(size_t)r * 64 + lane];
    }
    acc *= dis[wid];

    // combine: out[ch]=sum_b w[hd*4+b]*agg[b*16+fh], lane produces ch=lane and ch=64+lane
    int fh = lane & 15;
    float a0 = __shfl(acc, fh, 64);
    float a1 = __shfl(acc, 16 + fh, 64);
    float a2 = __shfl(acc, 32 + fh, 64);
    float a3 = __shfl(acc, 48 + fh, 64);
    const float* wn = wcomb + (size_t)wid * 32;
    int hd = lane >> 4;
    float s1 = bias[lane];
    float s2 = bias[64 + lane];
    s1 = fmaf(wn[hd * 4 + 0], a0, s1);
    s1 = fmaf(wn[hd * 4 + 1], a1, s1);
    s1 = fmaf(wn[hd * 4 + 2], a2, s1);
    s1 = fmaf(wn[hd * 4 + 3], a3, s1);
    s2 = fmaf(wn[(4 + hd) * 4 + 0], a0, s2);
    s2 = fmaf(wn[(4 + hd) * 4 + 1], a1, s2);
    s2 = fmaf(wn[(4 + hd) * 4 + 2], a2, s2);
    s2 = fmaf(wn[(4 + hd) * 4 + 3], a3, s2);
    if (do_relu) {
        s1 = fmaxf(s1, 0.f);
        s2 = fmaxf(s2, 0.f);
    }
    h[(size_t)wid * 128 + lane] = s1;
    h[(size_t)wid * 128 + 64 + lane] = s2;
}

// ---------------- per-node classifier projections ----------------
__global__ __launch_bounds__(256) void k_cls(
    const float* __restrict__ h, const float* __restrict__ Wcls,
    const float* __restrict__ bcls, float* __restrict__ p, int n)
{
    int t = blockIdx.x * 256 + threadIdx.x;
    int node = t >> 6, l = t & 63;
    if (node >= n) return;
    float a = h[(size_t)node * 128 + l];
    float b = h[(size_t)node * 128 + 64 + l];
    float r0 = a * Wcls[l * 2 + 0] + b * Wcls[(64 + l) * 2 + 0];
    float r1 = a * Wcls[l * 2 + 1] + b * Wcls[(64 + l) * 2 + 1];
    float r2 = a * Wcls[(128 + l) * 2 + 0] + b * Wcls[(192 + l) * 2 + 0];
    float r3 = a * Wcls[(128 + l) * 2 + 1] + b * Wcls[(192 + l) * 2 + 1];
#pragma unroll
    for (int off = 32; off; off >>= 1) {
        r0 += __shfl_xor(r0, off, 64);
        r1 += __shfl_xor(r1, off, 64);
        r2 += __shfl_xor(r2, off, 64);
        r3 += __shfl_xor(r3, off, 64);
    }
    if (l == 0) {
        p[node * 4 + 0] = r0 + bcls[0];
        p[node * 4 + 1] = r1 + bcls[1];
        p[node * 4 + 2] = r2;
        p[node * 4 + 3] = r3;
    }
}

__global__ void k_edge(const int* __restrict__ ei, const float* __restrict__ p,
                       float* __restrict__ out, int e)
{
    int t = blockIdx.x * blockDim.x + threadIdx.x;
    if (t >= e) return;
    int r = ei[t];
    int c = ei[e + t];
    float2 pt = *(const float2*)(p + r * 4);
    float2 pb = *(const float2*)(p + c * 4 + 2);
    float2 o;
    o.x = pt.x + pb.x;
    o.y = pt.y + pb.y;
    *(float2*)(out + t * 2) = o;
}

extern "C" void kernel_launch(void* const* d_in, const int* in_sizes, int n_in,
                              void* d_out, int out_size, void* d_ws, size_t ws_size,
                              hipStream_t stream) {
    const float* x    = (const float*)d_in[0];
    const int*   ei   = (const int*)d_in[1];
    const float* Wb1  = (const float*)d_in[2];
    const float* Wc1  = (const float*)d_in[3];
    const float* bc1  = (const float*)d_in[4];
    const float* b1   = (const float*)d_in[5];
    const float* Wb2  = (const float*)d_in[6];
    const float* Wc2  = (const float*)d_in[7];
    const float* bc2  = (const float*)d_in[8];
    const float* b2   = (const float*)d_in[9];
    const float* Wcls = (const float*)d_in[10];
    const float* bcls = (const float*)d_in[11];
    float* out = (float*)d_out;

    char* ws = (char*)d_ws;
    size_t off = 0;
    auto alloc = [&](size_t elems) { void* p = ws + off; off += elems * 4; return p; };

    float* dis    = (float*)alloc(50048);
    float* bases  = (float*)alloc((size_t)NN * 64);
    float* wcomb  = (float*)alloc((size_t)NN * 32);
    float* h      = (float*)alloc((size_t)NN * 128);
    float* p      = (float*)alloc((size_t)NN * 4);
    int*   cnt    = (int*)alloc(50048);
    int*   starts = (int*)alloc(50048);
    int*   cursor = (int*)alloc(50048);
    int*   bsum   = (int*)alloc(256);
    int*   boff   = (int*)alloc(256);
    int*   csr    = (int*)alloc(EE);

    const int B = 256;
    int gN    = (NN + B - 1) / B;        // 196
    int gE    = (EE + B - 1) / B;        // 3125
    int gN64  = (NN * 64) / B;           // 12500
    dim3 gG(gN, 3);

    // degree + symnorm + CSR build (shared by both layers)
    k_zero_i<<<gN, B, 0, stream>>>(cnt, NN);
    k_count<<<gE, B, 0, stream>>>(ei + EE, cnt, EE);
    k_dis<<<gN, B, 0, stream>>>(cnt, dis, NN);
    k_scan1<<<gN, B, 0, stream>>>(cnt, starts, bsum, NN);
    k_scan2<<<1, B, 0, stream>>>(bsum, boff, gN);
    k_scan3<<<gN, B, 0, stream>>>(starts, cursor, boff, NN);
    k_fill<<<gE, B, 0, stream>>>(ei, cursor, csr, EE);

    // conv1
    k_gemm<<<gG, B, 0, stream>>>(x, Wb1, Wc1, bc1, dis, bases, wcomb, NN);
    k_agg<<<gN64, B, 0, stream>>>(csr, starts, cnt, bases, dis, wcomb, b1, h, NN, 1);

    // conv2
    k_gemm<<<gG, B, 0, stream>>>(h, Wb2, Wc2, bc2, dis, bases, wcomb, NN);
    k_agg<<<gN64, B, 0, stream>>>(csr, starts, cnt, bases, dis, wcomb, b2, h, NN, 0);

    // edge classifier
    k_cls<<<gN64, B, 0, stream>>>(h, Wcls, bcls, p, NN);
    k_edge<<<gE, B, 0, stream>>>(ei, p, out, EE);
}

// Round 3
// 329.725 us; speedup vs baseline: 2.3618x; 1.1773x over previous
//
#include <hip/hip_runtime.h>

#define NN 50000
#define EE 800000
// IN = HID = 128, BASES*FH = 64, HEADS*BASES = 32

// ---------------- degree count ----------------
__global__ void k_count(const int* __restrict__ col, int* cnt, int e) {
    int i = blockIdx.x * blockDim.x + threadIdx.x;
    if (i < e) atomicAdd(&cnt[col[i]], 1);
}

// ---------------- scans (+ dis folded into scan1) ----------------
__global__ void k_scan1(const int* __restrict__ cnt, int* starts, int* bsum,
                        float* dis, int n) {
    __shared__ int s[256];
    int tid = threadIdx.x;
    int i = blockIdx.x * 256 + tid;
    int v = (i < n) ? cnt[i] : 0;
    if (i < n) dis[i] = rsqrtf((float)v + 1.0f);  // +1 self loop
    s[tid] = v;
    __syncthreads();
    for (int off = 1; off < 256; off <<= 1) {
        int t = 0;
        if (tid >= off) t = s[tid - off];
        __syncthreads();
        if (tid >= off) s[tid] += t;
        __syncthreads();
    }
    if (i < n) starts[i] = s[tid] - v;
    if (tid == 255) bsum[blockIdx.x] = s[255];
}

__global__ void k_scan2(const int* __restrict__ bsum, int* boff, int nb) {
    __shared__ int s[256];
    int tid = threadIdx.x;
    int v = (tid < nb) ? bsum[tid] : 0;
    s[tid] = v;
    __syncthreads();
    for (int off = 1; off < 256; off <<= 1) {
        int t = 0;
        if (tid >= off) t = s[tid - off];
        __syncthreads();
        if (tid >= off) s[tid] += t;
        __syncthreads();
    }
    if (tid < nb) boff[tid] = s[tid] - v;
}

__global__ void k_scan3(int* starts, int* cursor, const int* __restrict__ boff, int n) {
    int i = blockIdx.x * blockDim.x + threadIdx.x;
    if (i < n) {
        int st = starts[i] + boff[i >> 8];
        starts[i] = st;
        cursor[i] = st;
    }
}

__global__ void k_fill(const int* __restrict__ ei, int* cursor, int* csr, int e) {
    int i = blockIdx.x * blockDim.x + threadIdx.x;
    if (i < e) {
        int r = ei[i];
        int c = ei[e + i];
        int pos = atomicAdd(&cursor[c], 1);
        csr[pos] = r;
    }
}

// ---------------- GEMM: column-group split (y=0,1 -> bases*dis ; y=2 -> wcomb) ----------------
__global__ __launch_bounds__(256) void k_gemm(
    const float* __restrict__ x, const float* __restrict__ Wb,
    const float* __restrict__ Wc, const float* __restrict__ bc,
    const float* __restrict__ dis,
    float* __restrict__ bases, float* __restrict__ wcomb, int n)
{
    int row = blockIdx.x * 256 + threadIdx.x;
    int grp = blockIdx.y;
    if (row >= n) return;
    float acc[32];
#pragma unroll
    for (int c = 0; c < 32; c++) acc[c] = 0.f;

    const float* W = (grp < 2) ? (Wb + grp * 32) : Wc;
    int ldw = (grp < 2) ? 64 : 32;

    const float4* xr = (const float4*)(x + (size_t)row * 128);
    for (int k4 = 0; k4 < 32; k4++) {
        float4 xv = xr[k4];
#pragma unroll
        for (int j = 0; j < 4; j++) {
            float xs = (j == 0) ? xv.x : (j == 1) ? xv.y : (j == 2) ? xv.z : xv.w;
            const float* wk = W + (k4 * 4 + j) * ldw;
#pragma unroll
            for (int c = 0; c < 32; c++) acc[c] = fmaf(xs, wk[c], acc[c]);
        }
    }
    if (grp < 2) {
        float d = dis[row];
        float4* bo = (float4*)(bases + (size_t)row * 64 + grp * 32);
#pragma unroll
        for (int c = 0; c < 8; c++)
            bo[c] = make_float4(acc[4*c] * d, acc[4*c+1] * d, acc[4*c+2] * d, acc[4*c+3] * d);
    } else {
        float4* wo = (float4*)(wcomb + (size_t)row * 32);
#pragma unroll
        for (int c = 0; c < 8; c++)
            wo[c] = make_float4(acc[4*c] + bc[4*c], acc[4*c+1] + bc[4*c+1],
                                acc[4*c+2] + bc[4*c+2], acc[4*c+3] + bc[4*c+3]);
    }
}

// ---------------- fused aggregate (float4 CSR gather, 4 edges/iter) + combine ----------------
// LAYER2==0: + bias + relu -> store h.  LAYER2==1: + bias, then edge-cls projection -> store p[n,4].
template<int LAYER2>
__global__ __launch_bounds__(256) void k_agg(
    const int* __restrict__ csr, const int* __restrict__ starts,
    const int* __restrict__ cnt, const float* __restrict__ bs,
    const float* __restrict__ dis, const float* __restrict__ wcomb,
    const float* __restrict__ bias, float* __restrict__ h,
    const float* __restrict__ Wcls, const float* __restrict__ bcls,
    float* __restrict__ p, int n)
{
    int wid = (blockIdx.x * 256 + threadIdx.x) >> 6;
    int lane = threadIdx.x & 63;
    if (wid >= n) return;
    int start = starts[wid];
    int deg = cnt[wid];
    int g = lane >> 4, q = lane & 15;

    const float4* bs4 = (const float4*)bs;
    float4 acc4 = make_float4(0.f, 0.f, 0.f, 0.f);
    if (g == 0) acc4 = bs4[(size_t)wid * 16 + q];  // self-loop term (pre-scaled by dis)

    int j = 0;
    for (; j + 8 <= deg; j += 8) {  // 8 edges in flight
        int r0 = csr[start + j + g];
        int r1 = csr[start + j + 4 + g];
        float4 v0 = bs4[(size_t)r0 * 16 + q];
        float4 v1 = bs4[(size_t)r1 * 16 + q];
        acc4.x += v0.x + v1.x;
        acc4.y += v0.y + v1.y;
        acc4.z += v0.z + v1.z;
        acc4.w += v0.w + v1.w;
    }
    int last = start + deg - 1;
    for (; j < deg; j += 4) {
        int idx = start + j + g;
        int r = csr[min(idx, last)];
        float4 v = bs4[(size_t)r * 16 + q];
        float m = (j + g < deg) ? 1.f : 0.f;
        acc4.x = fmaf(v.x, m, acc4.x);
        acc4.y = fmaf(v.y, m, acc4.y);
        acc4.z = fmaf(v.z, m, acc4.z);
        acc4.w = fmaf(v.w, m, acc4.w);
    }

    // reduce across the 4 edge-slots (g): xor-16, xor-32
    acc4.x += __shfl_xor(acc4.x, 16, 64);
    acc4.y += __shfl_xor(acc4.y, 16, 64);
    acc4.z += __shfl_xor(acc4.z, 16, 64);
    acc4.w += __shfl_xor(acc4.w, 16, 64);
    acc4.x += __shfl_xor(acc4.x, 32, 64);
    acc4.y += __shfl_xor(acc4.y, 32, 64);
    acc4.z += __shfl_xor(acc4.z, 32, 64);
    acc4.w += __shfl_xor(acc4.w, 32, 64);

    float d = dis[wid];
    acc4.x *= d; acc4.y *= d; acc4.z *= d; acc4.w *= d;

    // transpose float4-per-lane(q) -> scalar-per-lane: acc = agg[lane]
    int src = lane >> 2;
    float t0 = __shfl(acc4.x, src, 64);
    float t1 = __shfl(acc4.y, src, 64);
    float t2 = __shfl(acc4.z, src, 64);
    float t3 = __shfl(acc4.w, src, 64);
    int c = lane & 3;
    float acc = (c == 0) ? t0 : (c == 1) ? t1 : (c == 2) ? t2 : t3;

    // combine: ch=lane and ch=64+lane
    int fh = lane & 15;
    float a0 = __shfl(acc, fh, 64);
    float a1 = __shfl(acc, 16 + fh, 64);
    float a2 = __shfl(acc, 32 + fh, 64);
    float a3 = __shfl(acc, 48 + fh, 64);
    const float* wn = wcomb + (size_t)wid * 32;
    int hd = lane >> 4;
    float s1 = bias[lane];
    float s2 = bias[64 + lane];
    s1 = fmaf(wn[hd * 4 + 0], a0, s1);
    s1 = fmaf(wn[hd * 4 + 1], a1, s1);
    s1 = fmaf(wn[hd * 4 + 2], a2, s1);
    s1 = fmaf(wn[hd * 4 + 3], a3, s1);
    s2 = fmaf(wn[(4 + hd) * 4 + 0], a0, s2);
    s2 = fmaf(wn[(4 + hd) * 4 + 1], a1, s2);
    s2 = fmaf(wn[(4 + hd) * 4 + 2], a2, s2);
    s2 = fmaf(wn[(4 + hd) * 4 + 3], a3, s2);

    if (!LAYER2) {
        s1 = fmaxf(s1, 0.f);
        s2 = fmaxf(s2, 0.f);
        h[(size_t)wid * 128 + lane] = s1;
        h[(size_t)wid * 128 + 64 + lane] = s2;
    } else {
        // edge-cls projection: p[wid] = [h.Wtop0+bc0, h.Wtop1+bc1, h.Wbot0, h.Wbot1]
        float r0 = s1 * Wcls[lane * 2 + 0] + s2 * Wcls[(64 + lane) * 2 + 0];
        float r1 = s1 * Wcls[lane * 2 + 1] + s2 * Wcls[(64 + lane) * 2 + 1];
        float r2 = s1 * Wcls[(128 + lane) * 2 + 0] + s2 * Wcls[(192 + lane) * 2 + 0];
        float r3 = s1 * Wcls[(128 + lane) * 2 + 1] + s2 * Wcls[(192 + lane) * 2 + 1];
#pragma unroll
        for (int off = 32; off; off >>= 1) {
            r0 += __shfl_xor(r0, off, 64);
            r1 += __shfl_xor(r1, off, 64);
            r2 += __shfl_xor(r2, off, 64);
            r3 += __shfl_xor(r3, off, 64);
        }
        if (lane == 0) {
            p[wid * 4 + 0] = r0 + bcls[0];
            p[wid * 4 + 1] = r1 + bcls[1];
            p[wid * 4 + 2] = r2;
            p[wid * 4 + 3] = r3;
        }
    }
}

__global__ void k_edge(const int* __restrict__ ei, const float* __restrict__ p,
                       float* __restrict__ out, int e)
{
    int t = blockIdx.x * blockDim.x + threadIdx.x;
    if (t >= e) return;
    int r = ei[t];
    int c = ei[e + t];
    float2 pt = *(const float2*)(p + r * 4);
    float2 pb = *(const float2*)(p + c * 4 + 2);
    float2 o;
    o.x = pt.x + pb.x;
    o.y = pt.y + pb.y;
    *(float2*)(out + t * 2) = o;
}

extern "C" void kernel_launch(void* const* d_in, const int* in_sizes, int n_in,
                              void* d_out, int out_size, void* d_ws, size_t ws_size,
                              hipStream_t stream) {
    const float* x    = (const float*)d_in[0];
    const int*   ei   = (const int*)d_in[1];
    const float* Wb1  = (const float*)d_in[2];
    const float* Wc1  = (const float*)d_in[3];
    const float* bc1  = (const float*)d_in[4];
    const float* b1   = (const float*)d_in[5];
    const float* Wb2  = (const float*)d_in[6];
    const float* Wc2  = (const float*)d_in[7];
    const float* bc2  = (const float*)d_in[8];
    const float* b2   = (const float*)d_in[9];
    const float* Wcls = (const float*)d_in[10];
    const float* bcls = (const float*)d_in[11];
    float* out = (float*)d_out;

    char* ws = (char*)d_ws;
    size_t off = 0;
    auto alloc = [&](size_t elems) { void* pp = ws + off; off += elems * 4; return pp; };

    float* dis    = (float*)alloc(50048);
    float* bases  = (float*)alloc((size_t)NN * 64);
    float* wcomb  = (float*)alloc((size_t)NN * 32);
    float* h      = (float*)alloc((size_t)NN * 128);
    float* p      = (float*)alloc((size_t)NN * 4);
    int*   cnt    = (int*)alloc(50048);
    int*   starts = (int*)alloc(50048);
    int*   cursor = (int*)alloc(50048);
    int*   bsum   = (int*)alloc(256);
    int*   boff   = (int*)alloc(256);
    int*   csr    = (int*)alloc(EE);

    const int B = 256;
    int gN   = (NN + B - 1) / B;   // 196
    int gE   = (EE + B - 1) / B;   // 3125
    int gN64 = (NN * 64) / B;      // 12500
    dim3 gG(gN, 3);

    // CSR build (shared by both layers)
    hipMemsetAsync(cnt, 0, NN * sizeof(int), stream);
    k_count<<<gE, B, 0, stream>>>(ei + EE, cnt, EE);
    k_scan1<<<gN, B, 0, stream>>>(cnt, starts, bsum, dis, NN);
    k_scan2<<<1, B, 0, stream>>>(bsum, boff, gN);
    k_scan3<<<gN, B, 0, stream>>>(starts, cursor, boff, NN);
    k_fill<<<gE, B, 0, stream>>>(ei, cursor, csr, EE);

    // conv1
    k_gemm<<<gG, B, 0, stream>>>(x, Wb1, Wc1, bc1, dis, bases, wcomb, NN);
    k_agg<0><<<gN64, B, 0, stream>>>(csr, starts, cnt, bases, dis, wcomb, b1, h,
                                     Wcls, bcls, p, NN);

    // conv2 (+ fused edge-cls projection)
    k_gemm<<<gG, B, 0, stream>>>(h, Wb2, Wc2, bc2, dis, bases, wcomb, NN);
    k_agg<1><<<gN64, B, 0, stream>>>(csr, starts, cnt, bases, dis, wcomb, b2, h,
                                     Wcls, bcls, p, NN);

    // edge output
    k_edge<<<gE, B, 0, stream>>>(ei, p, out, EE);
}